// Round 12
// baseline (113.915 us; speedup 1.0000x reference)
//
#include <hip/hip_runtime.h>
#include <cstdint>

typedef __bf16 bf16x8 __attribute__((ext_vector_type(8)));
typedef __bf16 bf16x4 __attribute__((ext_vector_type(4)));
typedef float  f32x4  __attribute__((ext_vector_type(4)));

static constexpr int kB = 2, kT = 2048, kC = 1024, kH = 16, kD = 64;
static constexpr int kK = 1024;  // GEMM inner dim (= kC)

__device__ __forceinline__ uint16_t f2bf(float f) {
  uint32_t u = __builtin_bit_cast(uint32_t, f);
  u += 0x7FFFu + ((u >> 16) & 1u);
  return (uint16_t)(u >> 16);
}

__device__ __forceinline__ void gl_lds16(const void* g, void* l) {
  __builtin_amdgcn_global_load_lds((__attribute__((address_space(1))) void*)(void*)g,
                                   (__attribute__((address_space(3))) void*)l, 16, 0, 0);
}

// ---------------- fused prep: xp = bf16(x+pe); w casts ----------------
__global__ __launch_bounds__(256) void prep_all(const float* __restrict__ x,
                                                const float* __restrict__ pe,
                                                const float* __restrict__ wqkv,
                                                const float* __restrict__ wproj,
                                                uint16_t* __restrict__ xp,
                                                uint16_t* __restrict__ wq,
                                                uint16_t* __restrict__ wp) {
  constexpr int NX = kB * kT * kC / 4;   // 1048576
  constexpr int NWQ = 3 * kC * kC / 4;   // 786432
  const int i = blockIdx.x * 256 + threadIdx.x;
  if (i < NX) {
    const float4 xv = ((const float4*)x)[i];
    const int c4 = i & (kC / 4 - 1);
    const int t = (i / (kC / 4)) & (kT - 1);
    const float4 pv = ((const float4*)pe)[t * (kC / 4) + c4];
    ushort4 o;
    o.x = f2bf(xv.x + pv.x);
    o.y = f2bf(xv.y + pv.y);
    o.z = f2bf(xv.z + pv.z);
    o.w = f2bf(xv.w + pv.w);
    ((ushort4*)xp)[i] = o;
  } else if (i < NX + NWQ) {
    const int j = i - NX;
    const float4 v = ((const float4*)wqkv)[j];
    ushort4 u;
    u.x = f2bf(v.x); u.y = f2bf(v.y); u.z = f2bf(v.z); u.w = f2bf(v.w);
    ((ushort4*)wq)[j] = u;
  } else {
    const int j = i - NX - NWQ;
    const float4 v = ((const float4*)wproj)[j];
    ushort4 u;
    u.x = f2bf(v.x); u.y = f2bf(v.y); u.z = f2bf(v.z); u.w = f2bf(v.w);
    ((ushort4*)wp)[j] = u;
  }
}

// ---------------- QKV GEMM: 256x192 tile, 4-phase (R8 schedule) ----------
// M=4096 N=3072 K=1024 -> 16x16 = 256 blocks (100% CU fill). 8 waves
// (2M x 4N), wave 128x48 (phase = 64-row half x 48 cols). B-frags (2ks x 3nt)
// persist h0->h1. Stages: A = 4 gl_lds calls, B = 3. vmcnt(4)@p0/p2 drains
// the previous buffer's 7 calls; vmcnt(7)@p1/p3 is a no-op guard.
__global__ __launch_bounds__(512, 2) void gemm_qkv(const uint16_t* __restrict__ A,
                                                   const uint16_t* __restrict__ W,
                                                   uint16_t* __restrict__ qb,
                                                   uint16_t* __restrict__ kb,
                                                   uint16_t* __restrict__ vT) {
  __shared__ __align__(1024) char lds[114688];  // A: 2x32K @0 | B: 2x24K @65536
  const int tid = threadIdx.x;
  const int lane = tid & 63;
  const int wid = tid >> 6;
  const int l15 = lane & 15, l4 = lane >> 4;
  const int WM = wid >> 2, WN = wid & 3;  // 2 x 4
  const int orig = (int)blockIdx.x;
  const int xcd = orig & 7, j = orig >> 3;
  const int m0 = (xcd * 2 + (j & 1)) * 256;  // 16 m-tiles
  const int n0 = (j >> 1) * 192;             // 16 n-tiles

  f32x4 acc[2][4][3] = {};  // [row-half][mt][ntl]
  bf16x8 bfp[2][3];         // B frags, persist h0->h1

  auto stageA = [&](int buf, int kt) {
#pragma unroll
    for (int c = 0; c < 4; ++c) {
      const int off = (c * 512 + tid) * 16;  // 0..32K
      const int lr = off >> 7, cbl = off & 127;
      gl_lds16((const char*)A + ((size_t)(m0 + lr) * kK + kt * 64) * 2 +
                   (cbl ^ ((lr & 7) << 4)),
               lds + buf * 32768 + off);
    }
  };
  auto stageB = [&](int buf, int kt) {
#pragma unroll
    for (int c = 0; c < 3; ++c) {
      const int off = (c * 512 + tid) * 16;  // 0..24K
      const int lr = off >> 7, cbl = off & 127;
      gl_lds16((const char*)W + ((size_t)(n0 + lr) * kK + kt * 64) * 2 +
                   (cbl ^ ((lr & 7) << 4)),
               lds + 65536 + buf * 24576 + off);
    }
  };

#define QKV_PHASE(CBUF, H, SA, SBUF, KT, VM)                                      \
  {                                                                               \
    if (SA) stageA(SBUF, KT); else stageB(SBUF, KT);                              \
    if (VM == 4)                                                                  \
      asm volatile("s_waitcnt vmcnt(4)" ::: "memory");                            \
    else                                                                          \
      asm volatile("s_waitcnt vmcnt(7)" ::: "memory");                            \
    __builtin_amdgcn_s_barrier();                                                 \
    asm volatile("" ::: "memory");                                                \
    const char* Ab = lds + (CBUF)*32768;                                          \
    const char* Bb = lds + 65536 + (CBUF)*24576;                                  \
    if ((H) == 0) {                                                               \
      _Pragma("unroll") for (int ks = 0; ks < 2; ++ks)                            \
          _Pragma("unroll") for (int nt = 0; nt < 3; ++nt) {                      \
        const int lr = WN * 48 + nt * 16 + l15;                                   \
        bfp[ks][nt] = *(const bf16x8*)(Bb + lr * 128 +                            \
                                       ((ks * 64 + l4 * 16) ^ ((lr & 7) << 4)));  \
      }                                                                           \
    }                                                                             \
    _Pragma("unroll") for (int ks = 0; ks < 2; ++ks) {                            \
      bf16x8 af[4];                                                               \
      _Pragma("unroll") for (int mt = 0; mt < 4; ++mt) {                          \
        const int lr = (H)*128 + WM * 64 + mt * 16 + l15;                         \
        af[mt] = *(const bf16x8*)(Ab + lr * 128 +                                 \
                                  ((ks * 64 + l4 * 16) ^ ((lr & 7) << 4)));       \
      }                                                                           \
      __builtin_amdgcn_s_setprio(1);                                              \
      _Pragma("unroll") for (int mt = 0; mt < 4; ++mt)                            \
          _Pragma("unroll") for (int nt = 0; nt < 3; ++nt)                        \
              acc[H][mt][nt] = __builtin_amdgcn_mfma_f32_16x16x32_bf16(           \
                  af[mt], bfp[ks][nt], acc[H][mt][nt], 0, 0, 0);                  \
      __builtin_amdgcn_s_setprio(0);                                              \
    }                                                                             \
    asm volatile("" ::: "memory");                                                \
    __builtin_amdgcn_s_barrier();                                                 \
    asm volatile("" ::: "memory");                                                \
  }

  // prologue: buf0 <- kt0 (A 4 calls + B 3 calls = 7 outstanding)
  stageA(0, 0);
  stageB(0, 0);

  for (int i = 0; i < 8; ++i) {
    const int ktb1 = 2 * i + 1;
    const int ktb0 = (2 * i + 2 > 15) ? 15 : 2 * i + 2;  // clamp, never skip
    QKV_PHASE(0, 0, 1, 1, ktb1, 4);  // read buf0 h0; stage A-buf1
    QKV_PHASE(0, 1, 0, 1, ktb1, 7);  // read buf0 h1; stage B-buf1
    QKV_PHASE(1, 0, 1, 0, ktb0, 4);  // read buf1 h0; stage A-buf0
    QKV_PHASE(1, 1, 0, 0, ktb0, 7);  // read buf1 h1; stage B-buf0
  }
  asm volatile("s_waitcnt vmcnt(0)" ::: "memory");
  __builtin_amdgcn_s_barrier();
  asm volatile("" ::: "memory");

  // ---- epilogue: per-element q/k/v routing (tiles cross sections) ----
  const int b = m0 >> 11, tb = m0 & (kT - 1);
#pragma unroll
  for (int h = 0; h < 2; ++h)
#pragma unroll
    for (int mt = 0; mt < 4; ++mt)
#pragma unroll
      for (int nt = 0; nt < 3; ++nt)
#pragma unroll
        for (int r = 0; r < 4; ++r) {
          const int m = h * 128 + WM * 64 + mt * 16 + l4 * 4 + r;
          const int t = tb + m;
          const int n = n0 + WN * 48 + nt * 16 + l15;
          const int sec = n >> 10, nn = n & (kC - 1);
          const int hh = nn >> 6, d = nn & 63;
          const uint16_t v = f2bf(acc[h][mt][nt][r]);
          if (sec == 0)
            qb[((size_t)((b * kH + hh) * kT + t)) * kD + d] = v;
          else if (sec == 1)
            kb[((size_t)((b * kH + hh) * kT + t)) * kD + d] = v;
          else
            vT[((size_t)((b * kH + hh) * kD + d)) * kT + t] = v;
        }
#undef QKV_PHASE
}

// ---------------- proj GEMM: 128x128 tile, 4-phase port, f32 out ----------
// 256 blocks (100% fill), 4 waves (2M x 2N), wave 64x64; phase = 64-row half;
// B-frags persist h0->h1. A/B stages = 4 gl_lds calls each; vmcnt(4)@p0/p2,
// vmcnt(8)@p1/p3 (no-op guard). LDS 64 KiB.
__global__ __launch_bounds__(256, 2) void gemm_proj(const uint16_t* __restrict__ A,
                                                    const uint16_t* __restrict__ W,
                                                    float* __restrict__ out) {
  __shared__ __align__(1024) char lds[65536];  // A: 2x16K @0 | B: 2x16K @32768
  const int tid = threadIdx.x;
  const int lane = tid & 63;
  const int wid = tid >> 6;
  const int l15 = lane & 15, l4 = lane >> 4;
  const int WM = wid >> 1, WN = wid & 1;  // 2 x 2
  const int orig = (int)blockIdx.x;
  const int xcd = orig & 7, j = orig >> 3;
  const int m0 = (xcd * 4 + (j & 3)) * 128;  // 32 m-tiles
  const int n0 = (j >> 2) * 128;             // 8 n-tiles

  f32x4 acc[2][2][4] = {};  // [row-half][mt][nt]
  bf16x8 bfp[2][4];         // B frags, persist h0->h1

  auto stage = [&](int isA, int buf, int kt) {
#pragma unroll
    for (int c = 0; c < 4; ++c) {
      const int off = (c * 256 + tid) * 16;  // 0..16K
      const int lr = off >> 7, cbl = off & 127;
      const size_t grow = (size_t)((isA ? m0 : n0) + lr) * kK + kt * 64;
      gl_lds16((const char*)(isA ? A : W) + grow * 2 + (cbl ^ ((lr & 7) << 4)),
               lds + (isA ? 0 : 32768) + buf * 16384 + off);
    }
  };

#define PRJ_PHASE(CBUF, H, SA, SBUF, KT, VM)                                      \
  {                                                                               \
    stage(SA, SBUF, KT);                                                          \
    if (VM == 4)                                                                  \
      asm volatile("s_waitcnt vmcnt(4)" ::: "memory");                            \
    else                                                                          \
      asm volatile("s_waitcnt vmcnt(8)" ::: "memory");                            \
    __builtin_amdgcn_s_barrier();                                                 \
    asm volatile("" ::: "memory");                                                \
    const char* Ab = lds + (CBUF)*16384;                                          \
    const char* Bb = lds + 32768 + (CBUF)*16384;                                  \
    if ((H) == 0) {                                                               \
      _Pragma("unroll") for (int ks = 0; ks < 2; ++ks)                            \
          _Pragma("unroll") for (int nt = 0; nt < 4; ++nt) {                      \
        const int lr = WN * 64 + nt * 16 + l15;                                   \
        bfp[ks][nt] = *(const bf16x8*)(Bb + lr * 128 +                            \
                                       ((ks * 64 + l4 * 16) ^ ((lr & 7) << 4)));  \
      }                                                                           \
    }                                                                             \
    _Pragma("unroll") for (int ks = 0; ks < 2; ++ks) {                            \
      bf16x8 af[2];                                                               \
      _Pragma("unroll") for (int mt = 0; mt < 2; ++mt) {                          \
        const int lr = (H)*64 + WM * 32 + mt * 16 + l15;                          \
        af[mt] = *(const bf16x8*)(Ab + lr * 128 +                                 \
                                  ((ks * 64 + l4 * 16) ^ ((lr & 7) << 4)));       \
      }                                                                           \
      __builtin_amdgcn_s_setprio(1);                                              \
      _Pragma("unroll") for (int mt = 0; mt < 2; ++mt)                            \
          _Pragma("unroll") for (int nt = 0; nt < 4; ++nt)                        \
              acc[H][mt][nt] = __builtin_amdgcn_mfma_f32_16x16x32_bf16(           \
                  af[mt], bfp[ks][nt], acc[H][mt][nt], 0, 0, 0);                  \
      __builtin_amdgcn_s_setprio(0);                                              \
    }                                                                             \
    asm volatile("" ::: "memory");                                                \
    __builtin_amdgcn_s_barrier();                                                 \
    asm volatile("" ::: "memory");                                                \
  }

  // prologue: buf0 <- kt0 (A + B = 8 outstanding)
  stage(1, 0, 0);
  stage(0, 0, 0);

  for (int i = 0; i < 8; ++i) {
    const int ktb1 = 2 * i + 1;
    const int ktb0 = (2 * i + 2 > 15) ? 15 : 2 * i + 2;  // clamp, never skip
    PRJ_PHASE(0, 0, 1, 1, ktb1, 4);  // read buf0 h0; stage A-buf1
    PRJ_PHASE(0, 1, 0, 1, ktb1, 8);  // read buf0 h1; stage B-buf1
    PRJ_PHASE(1, 0, 1, 0, ktb0, 4);  // read buf1 h0; stage A-buf0
    PRJ_PHASE(1, 1, 0, 0, ktb0, 8);  // read buf1 h1; stage B-buf0
  }
  asm volatile("s_waitcnt vmcnt(0)" ::: "memory");
  __builtin_amdgcn_s_barrier();
  asm volatile("" ::: "memory");

#pragma unroll
  for (int h = 0; h < 2; ++h)
#pragma unroll
    for (int mt = 0; mt < 2; ++mt)
#pragma unroll
      for (int nt = 0; nt < 4; ++nt)
#pragma unroll
        for (int r = 0; r < 4; ++r) {
          const int m = m0 + h * 64 + WM * 32 + mt * 16 + l4 * 4 + r;
          const int n = n0 + WN * 64 + nt * 16 + l15;
          out[(size_t)m * kC + n] = acc[h][mt][nt][r];
        }
#undef PRJ_PHASE
}

// ---------------- flash attention (causal), swapped-QK (R11 proven) ----------
__global__ __launch_bounds__(256, 4) void attn(const uint16_t* __restrict__ qb,
                                               const uint16_t* __restrict__ kb,
                                               const uint16_t* __restrict__ vT,
                                               uint16_t* __restrict__ y) {
  // LDS: K[2] @ 0/8192 | V[2] @ 16384/24576 | P @ 32768 + wid*2048
  __shared__ __align__(1024) char lds[40960];
  const int lane = threadIdx.x & 63;
  const int wid = threadIdx.x >> 6;
  const int l15 = lane & 15, l4 = lane >> 4;
  const int bh = blockIdx.x;
  const int qt = (int)(gridDim.y - 1) - (int)blockIdx.y;  // LPT: long first
  const int q0 = qt * 64 + wid * 16;  // this wave's first q row
  const size_t base = (size_t)bh * kT * kD;
  const uint16_t* Q = qb + base;
  const uint16_t* Kp = kb + base;
  const uint16_t* Vt = vT + base;
  char* P = lds + 32768 + wid * 2048;
  const int xr = (l15 & 7) << 4;

  // Q fragments, scaled by log2(e)/sqrt(d) (exp2-domain softmax)
  bf16x8 qf[2];
#pragma unroll
  for (int ks = 0; ks < 2; ++ks) {
    bf16x8 t = *(const bf16x8*)(Q + (size_t)(q0 + l15) * kD + ks * 32 + l4 * 8);
#pragma unroll
    for (int i = 0; i < 8; ++i) t[i] = (__bf16)((float)t[i] * 0.1803368801f);
    qf[ks] = t;
  }
  bf16x8 ones;
#pragma unroll
  for (int i = 0; i < 8; ++i) ones[i] = (__bf16)1.0f;

  float m_ = -1e30f;                // per-lane; kept row-uniform
  f32x4 o[4];                       // O^T[d = nt*16 + l4*4 + r][q = l15]
  f32x4 ol = {0.f, 0.f, 0.f, 0.f};  // ones-row accumulator: ol[*] = l(q=l15)
#pragma unroll
  for (int nt = 0; nt < 4; ++nt) o[nt] = (f32x4){0.f, 0.f, 0.f, 0.f};

  const int nkt = qt + 1;  // wave-uniform

  auto STAGE = [&](int bi, int k0) {
#pragma unroll
    for (int c = 0; c < 2; ++c) {
      const int call = wid * 2 + c;
      const int row = call * 8 + (lane >> 3);
      const int colb = (((lane & 7) ^ ((lane >> 3) & 7)) << 4);
      gl_lds16((const char*)Kp + ((size_t)(k0 + row) * kD) * 2 + colb,
               lds + bi * 8192 + call * 1024);
      gl_lds16((const char*)Vt + ((size_t)row * kT + k0) * 2 + colb,
               lds + 16384 + bi * 8192 + call * 1024);
    }
  };

  int cur = 0;
  STAGE(0, 0);
  for (int kt = 0; kt < nkt; ++kt) {
    const int k0 = kt * 64;
    const bool hasnext = (kt + 1 < nkt);
    if (hasnext) STAGE(cur ^ 1, k0 + 64);
    if (hasnext)
      asm volatile("s_waitcnt vmcnt(4)" ::: "memory");
    else
      asm volatile("s_waitcnt vmcnt(0)" ::: "memory");
    __builtin_amdgcn_s_barrier();
    asm volatile("" ::: "memory");

    const char* Kb = lds + cur * 8192;
    const char* Vb = lds + 16384 + cur * 8192;

    // S^T = K Q^T (log2-domain)
    f32x4 s[4] = {};
    __builtin_amdgcn_s_setprio(1);
#pragma unroll
    for (int ks = 0; ks < 2; ++ks)
#pragma unroll
      for (int nt = 0; nt < 4; ++nt) {
        const bf16x8 kf =
            *(const bf16x8*)(Kb + (nt * 16 + l15) * 128 + ((ks * 64 + l4 * 16) ^ xr));
        s[nt] = __builtin_amdgcn_mfma_f32_16x16x32_bf16(kf, qf[ks], s[nt], 0, 0, 0);
      }
    __builtin_amdgcn_s_setprio(0);

    if (kt == nkt - 1) {  // causal mask on diagonal tile
      const int qq = q0 + l15;
#pragma unroll
      for (int nt = 0; nt < 4; ++nt)
#pragma unroll
        for (int r = 0; r < 4; ++r)
          if (k0 + nt * 16 + l4 * 4 + r > qq) s[nt][r] = -1e30f;
    }

    // online softmax, defer-max; row-sum via ones-row MFMA below
    float pm = s[0][0];
#pragma unroll
    for (int nt = 0; nt < 4; ++nt)
#pragma unroll
      for (int r = 0; r < 4; ++r) pm = fmaxf(pm, s[nt][r]);
    if (!__all(pm <= m_ + 11.0f)) {
      float rm = fmaxf(pm, __shfl_xor(pm, 16));
      rm = fmaxf(rm, __shfl_xor(rm, 32));
      const float newm = fmaxf(m_, rm);
      const float sc = exp2f(m_ - newm);
      m_ = newm;
#pragma unroll
      for (int nt = 0; nt < 4; ++nt)
#pragma unroll
        for (int r = 0; r < 4; ++r) o[nt][r] *= sc;
#pragma unroll
      for (int r = 0; r < 4; ++r) ol[r] *= sc;
    }
#pragma unroll
    for (int nt = 0; nt < 4; ++nt)
#pragma unroll
      for (int r = 0; r < 4; ++r) s[nt][r] = exp2f(s[nt][r] - m_);

    // P -> LDS (bf16, 8B packed, XOR-swizzled)
#pragma unroll
    for (int nt = 0; nt < 4; ++nt) {
      bf16x4 pk;
#pragma unroll
      for (int r = 0; r < 4; ++r) pk[r] = (__bf16)s[nt][r];
      *(bf16x4*)(P + l15 * 128 + ((nt * 32 + l4 * 8) ^ xr)) = pk;
    }
    asm volatile("s_waitcnt lgkmcnt(0)" ::: "memory");
    __builtin_amdgcn_sched_barrier(0);

    // O^T += V^T P^T ; l += 1^T P^T (ones-row on the matrix pipe)
    bf16x8 pf[2];
#pragma unroll
    for (int ks = 0; ks < 2; ++ks)
      pf[ks] = *(const bf16x8*)(P + l15 * 128 + ((ks * 64 + l4 * 16) ^ xr));
    __builtin_amdgcn_s_setprio(1);
#pragma unroll
    for (int ks = 0; ks < 2; ++ks) {
#pragma unroll
      for (int nt = 0; nt < 4; ++nt) {
        const bf16x8 vf =
            *(const bf16x8*)(Vb + (nt * 16 + l15) * 128 + ((ks * 64 + l4 * 16) ^ xr));
        o[nt] = __builtin_amdgcn_mfma_f32_16x16x32_bf16(vf, pf[ks], o[nt], 0, 0, 0);
      }
      ol = __builtin_amdgcn_mfma_f32_16x16x32_bf16(ones, pf[ks], ol, 0, 0, 0);
    }
    __builtin_amdgcn_s_setprio(0);

    __builtin_amdgcn_s_barrier();
    asm volatile("" ::: "memory");
    cur ^= 1;
  }

  // epilogue: ol[0] holds the full row-sum (MFMA reduced over K)
  const float inv = 1.0f / ol[0];
  const int b = bh >> 4, h = bh & 15;
  const int q = q0 + l15;
#pragma unroll
  for (int nt = 0; nt < 4; ++nt) {
    bf16x4 yv;
#pragma unroll
    for (int r = 0; r < 4; ++r) yv[r] = (__bf16)(o[nt][r] * inv);
    *(bf16x4*)(y + ((size_t)(b * kT + q)) * kC + h * kD + nt * 16 + l4 * 4) = yv;
  }
}

extern "C" void kernel_launch(void* const* d_in, const int* in_sizes, int n_in,
                              void* d_out, int out_size, void* d_ws, size_t ws_size,
                              hipStream_t stream) {
  const float* x = (const float*)d_in[0];
  const float* wqkv = (const float*)d_in[1];
  const float* wproj = (const float*)d_in[2];
  const float* pe = (const float*)d_in[3];

  char* ws = (char*)d_ws;
  uint16_t* xp = (uint16_t*)(ws);                          // 8MB, reused as y
  uint16_t* wq = (uint16_t*)(ws + (size_t)(8u << 20));     // 6MB
  uint16_t* wp = (uint16_t*)(ws + (size_t)(14u << 20));    // 2MB
  uint16_t* qbuf = (uint16_t*)(ws + (size_t)(16u << 20));  // 8MB
  uint16_t* kbuf = (uint16_t*)(ws + (size_t)(24u << 20));  // 8MB
  uint16_t* vTb = (uint16_t*)(ws + (size_t)(32u << 20));   // 8MB (total 40MB)

  prep_all<<<dim3(8192), 256, 0, stream>>>(x, pe, wqkv, wproj, xp, wq, wp);

  // qkv = xp @ wqkv^T : M=4096, N=3072 (256x192 tiles, 256 blocks, 4-phase)
  gemm_qkv<<<dim3(256), 512, 0, stream>>>(xp, wq, qbuf, kbuf, vTb);

  // attention -> y (stored into xp buffer, [B,T,C] bf16)
  attn<<<dim3(kB * kH, kT / 64), 256, 0, stream>>>(qbuf, kbuf, vTb, xp);

  // out = y @ wproj^T : M=4096, N=1024, f32 out (128^2, 4-phase, 256 blocks)
  gemm_proj<<<dim3(256), 256, 0, stream>>>(xp, wp, (float*)d_out);
}

// Round 13
// 100.641 us; speedup vs baseline: 1.1319x; 1.1319x over previous
//
#include <hip/hip_runtime.h>
#include <cstdint>

typedef __bf16 bf16x8 __attribute__((ext_vector_type(8)));
typedef __bf16 bf16x4 __attribute__((ext_vector_type(4)));
typedef float  f32x4  __attribute__((ext_vector_type(4)));

static constexpr int kB = 2, kT = 2048, kC = 1024, kH = 16, kD = 64;
static constexpr int kK = 1024;  // GEMM inner dim (= kC)

__device__ __forceinline__ uint16_t f2bf(float f) {
  uint32_t u = __builtin_bit_cast(uint32_t, f);
  u += 0x7FFFu + ((u >> 16) & 1u);
  return (uint16_t)(u >> 16);
}

__device__ __forceinline__ void gl_lds16(const void* g, void* l) {
  __builtin_amdgcn_global_load_lds((__attribute__((address_space(1))) void*)(void*)g,
                                   (__attribute__((address_space(3))) void*)l, 16, 0, 0);
}

// ---------------- fused prep: xp = bf16(x+pe); w casts ----------------
__global__ __launch_bounds__(256) void prep_all(const float* __restrict__ x,
                                                const float* __restrict__ pe,
                                                const float* __restrict__ wqkv,
                                                const float* __restrict__ wproj,
                                                uint16_t* __restrict__ xp,
                                                uint16_t* __restrict__ wq,
                                                uint16_t* __restrict__ wp) {
  constexpr int NX = kB * kT * kC / 4;   // 1048576
  constexpr int NWQ = 3 * kC * kC / 4;   // 786432
  const int i = blockIdx.x * 256 + threadIdx.x;
  if (i < NX) {
    const float4 xv = ((const float4*)x)[i];
    const int c4 = i & (kC / 4 - 1);
    const int t = (i / (kC / 4)) & (kT - 1);
    const float4 pv = ((const float4*)pe)[t * (kC / 4) + c4];
    ushort4 o;
    o.x = f2bf(xv.x + pv.x);
    o.y = f2bf(xv.y + pv.y);
    o.z = f2bf(xv.z + pv.z);
    o.w = f2bf(xv.w + pv.w);
    ((ushort4*)xp)[i] = o;
  } else if (i < NX + NWQ) {
    const int j = i - NX;
    const float4 v = ((const float4*)wqkv)[j];
    ushort4 u;
    u.x = f2bf(v.x); u.y = f2bf(v.y); u.z = f2bf(v.z); u.w = f2bf(v.w);
    ((ushort4*)wq)[j] = u;
  } else {
    const int j = i - NX - NWQ;
    const float4 v = ((const float4*)wproj)[j];
    ushort4 u;
    u.x = f2bf(v.x); u.y = f2bf(v.y); u.z = f2bf(v.z); u.w = f2bf(v.w);
    ((ushort4*)wp)[j] = u;
  }
}

// ---------------- QKV GEMM: 256x256 tile, 4-phase (R8 proven, ~38us) --------
// 8 waves (2M x 4N); B-frags persist across row-half phases. 192 blocks.
__global__ __launch_bounds__(512, 2) void gemm_qkv(const uint16_t* __restrict__ A,
                                                   const uint16_t* __restrict__ W,
                                                   uint16_t* __restrict__ qb,
                                                   uint16_t* __restrict__ kb,
                                                   uint16_t* __restrict__ vT) {
  __shared__ __align__(1024) char lds[131072];  // A: 2x32K @0 | B: 2x32K @65536
  const int tid = threadIdx.x;
  const int lane = tid & 63;
  const int wid = tid >> 6;
  const int l15 = lane & 15, l4 = lane >> 4;
  const int WM = wid >> 2, WN = wid & 3;  // 2 x 4
  const int orig = (int)blockIdx.x;
  const int xcd = orig & 7, j = orig >> 3;
  const int m0 = (xcd * 2 + (j & 1)) * 256;  // 16 m-tiles
  const int n0 = (j >> 1) * 256;             // 12 n-tiles

  f32x4 acc[2][4][4] = {};  // [row-half][mt][nt]
  bf16x8 bfp[2][4];         // B frags, persist h0->h1

  auto stage = [&](int isA, int buf, int kt) {
#pragma unroll
    for (int c = 0; c < 4; ++c) {
      const int off = (c * 512 + tid) * 16;  // 0..32K
      const int lr = off >> 7, cbl = off & 127;
      const size_t grow = (size_t)((isA ? m0 : n0) + lr) * kK + kt * 64;
      gl_lds16((const char*)(isA ? A : W) + grow * 2 + (cbl ^ ((lr & 7) << 4)),
               lds + (isA ? 0 : 65536) + buf * 32768 + off);
    }
  };

#define QKV_PHASE(CBUF, H, SA, SBUF, KT, VM)                                      \
  {                                                                               \
    stage(SA, SBUF, KT);                                                          \
    if (VM == 4)                                                                  \
      asm volatile("s_waitcnt vmcnt(4)" ::: "memory");                            \
    else                                                                          \
      asm volatile("s_waitcnt vmcnt(8)" ::: "memory");                            \
    __builtin_amdgcn_s_barrier();                                                 \
    asm volatile("" ::: "memory");                                                \
    const char* Ab = lds + (CBUF)*32768;                                          \
    const char* Bb = lds + 65536 + (CBUF)*32768;                                  \
    if ((H) == 0) {                                                               \
      _Pragma("unroll") for (int ks = 0; ks < 2; ++ks)                            \
          _Pragma("unroll") for (int nt = 0; nt < 4; ++nt) {                      \
        const int lr = WN * 64 + nt * 16 + l15;                                   \
        bfp[ks][nt] = *(const bf16x8*)(Bb + lr * 128 +                            \
                                       ((ks * 64 + l4 * 16) ^ ((lr & 7) << 4)));  \
      }                                                                           \
    }                                                                             \
    _Pragma("unroll") for (int ks = 0; ks < 2; ++ks) {                            \
      bf16x8 af[4];                                                               \
      _Pragma("unroll") for (int mt = 0; mt < 4; ++mt) {                          \
        const int lr = (H)*128 + WM * 64 + mt * 16 + l15;                         \
        af[mt] = *(const bf16x8*)(Ab + lr * 128 +                                 \
                                  ((ks * 64 + l4 * 16) ^ ((lr & 7) << 4)));       \
      }                                                                           \
      __builtin_amdgcn_s_setprio(1);                                              \
      _Pragma("unroll") for (int mt = 0; mt < 4; ++mt)                            \
          _Pragma("unroll") for (int nt = 0; nt < 4; ++nt)                        \
              acc[H][mt][nt] = __builtin_amdgcn_mfma_f32_16x16x32_bf16(           \
                  af[mt], bfp[ks][nt], acc[H][mt][nt], 0, 0, 0);                  \
      __builtin_amdgcn_s_setprio(0);                                              \
    }                                                                             \
    asm volatile("" ::: "memory");                                                \
    __builtin_amdgcn_s_barrier();                                                 \
    asm volatile("" ::: "memory");                                                \
  }

  // prologue: buf0 <- kt0 (A then B) = 8 outstanding
  stage(1, 0, 0);
  stage(0, 0, 0);

  for (int i = 0; i < 8; ++i) {
    const int ktb1 = 2 * i + 1;
    const int ktb0 = (2 * i + 2 > 15) ? 15 : 2 * i + 2;  // clamp, never skip
    QKV_PHASE(0, 0, 1, 1, ktb1, 4);  // read buf0 h0; stage A-buf1
    QKV_PHASE(0, 1, 0, 1, ktb1, 8);  // read buf0 h1; stage B-buf1
    QKV_PHASE(1, 0, 1, 0, ktb0, 4);  // read buf1 h0; stage A-buf0
    QKV_PHASE(1, 1, 0, 0, ktb0, 8);  // read buf1 h1; stage B-buf0
  }
  asm volatile("s_waitcnt vmcnt(0)" ::: "memory");
  __builtin_amdgcn_s_barrier();
  asm volatile("" ::: "memory");

  // ---- epilogue (sec-pure 256-tiles): q/k direct, v via LDS transpose ----
  const int sec = n0 >> 10;
  const int b = m0 >> 11, tb = m0 & (kT - 1);
  if (sec < 2) {
    uint16_t* dst = (sec == 0) ? qb : kb;
#pragma unroll
    for (int h = 0; h < 2; ++h)
#pragma unroll
      for (int mt = 0; mt < 4; ++mt)
#pragma unroll
        for (int nt = 0; nt < 4; ++nt)
#pragma unroll
          for (int r = 0; r < 4; ++r) {
            const int m = h * 128 + WM * 64 + mt * 16 + l4 * 4 + r;
            const int nn = (n0 & (kC - 1)) + WN * 64 + nt * 16 + l15;
            const int hh = nn >> 6, d = nn & 63;
            dst[((size_t)((b * kH + hh) * kT + tb + m)) * kD + d] =
                f2bf(acc[h][mt][nt][r]);
          }
  } else {
    // v: bounce through LDS d-major [n][m] (free transpose), packed stores
#pragma unroll
    for (int h = 0; h < 2; ++h)
#pragma unroll
      for (int mt = 0; mt < 4; ++mt)
#pragma unroll
        for (int nt = 0; nt < 4; ++nt) {
          const int nl = WN * 64 + nt * 16 + l15;
          const int mb2 = (h * 128 + WM * 64 + mt * 16 + l4 * 4) * 2;
          ushort4 pk;
          pk.x = f2bf(acc[h][mt][nt][0]);
          pk.y = f2bf(acc[h][mt][nt][1]);
          pk.z = f2bf(acc[h][mt][nt][2]);
          pk.w = f2bf(acc[h][mt][nt][3]);
          *(ushort4*)(lds + nl * 512 + (mb2 ^ ((nl & 7) << 4))) = pk;
        }
    asm volatile("" ::: "memory");
    __builtin_amdgcn_s_barrier();
    asm volatile("" ::: "memory");
#pragma unroll
    for (int it = 0; it < 16; ++it) {
      const int chunk = it * 512 + tid;
      const int nr = chunk >> 5, mb = (chunk & 31) * 16;
      const bf16x8 v = *(const bf16x8*)(lds + nr * 512 + (mb ^ ((nr & 7) << 4)));
      const int nn = (n0 - 2048) + nr;
      const int hh = nn >> 6, d = nn & 63;
      *(bf16x8*)(vT + ((size_t)((b * kH + hh) * kD + d)) * kT + tb + (chunk & 31) * 8) = v;
    }
  }
#undef QKV_PHASE
}

// ---------------- proj GEMM: 128x128 tile, 4-phase (R12 proven, ~14us) ------
__global__ __launch_bounds__(256, 2) void gemm_proj(const uint16_t* __restrict__ A,
                                                    const uint16_t* __restrict__ W,
                                                    float* __restrict__ out) {
  __shared__ __align__(1024) char lds[65536];  // A: 2x16K @0 | B: 2x16K @32768
  const int tid = threadIdx.x;
  const int lane = tid & 63;
  const int wid = tid >> 6;
  const int l15 = lane & 15, l4 = lane >> 4;
  const int WM = wid >> 1, WN = wid & 1;  // 2 x 2
  const int orig = (int)blockIdx.x;
  const int xcd = orig & 7, j = orig >> 3;
  const int m0 = (xcd * 4 + (j & 3)) * 128;  // 32 m-tiles
  const int n0 = (j >> 2) * 128;             // 8 n-tiles

  f32x4 acc[2][2][4] = {};  // [row-half][mt][nt]
  bf16x8 bfp[2][4];         // B frags, persist h0->h1

  auto stage = [&](int isA, int buf, int kt) {
#pragma unroll
    for (int c = 0; c < 4; ++c) {
      const int off = (c * 256 + tid) * 16;  // 0..16K
      const int lr = off >> 7, cbl = off & 127;
      const size_t grow = (size_t)((isA ? m0 : n0) + lr) * kK + kt * 64;
      gl_lds16((const char*)(isA ? A : W) + grow * 2 + (cbl ^ ((lr & 7) << 4)),
               lds + (isA ? 0 : 32768) + buf * 16384 + off);
    }
  };

#define PRJ_PHASE(CBUF, H, SA, SBUF, KT, VM)                                      \
  {                                                                               \
    stage(SA, SBUF, KT);                                                          \
    if (VM == 4)                                                                  \
      asm volatile("s_waitcnt vmcnt(4)" ::: "memory");                            \
    else                                                                          \
      asm volatile("s_waitcnt vmcnt(8)" ::: "memory");                            \
    __builtin_amdgcn_s_barrier();                                                 \
    asm volatile("" ::: "memory");                                                \
    const char* Ab = lds + (CBUF)*16384;                                          \
    const char* Bb = lds + 32768 + (CBUF)*16384;                                  \
    if ((H) == 0) {                                                               \
      _Pragma("unroll") for (int ks = 0; ks < 2; ++ks)                            \
          _Pragma("unroll") for (int nt = 0; nt < 4; ++nt) {                      \
        const int lr = WN * 64 + nt * 16 + l15;                                   \
        bfp[ks][nt] = *(const bf16x8*)(Bb + lr * 128 +                            \
                                       ((ks * 64 + l4 * 16) ^ ((lr & 7) << 4)));  \
      }                                                                           \
    }                                                                             \
    _Pragma("unroll") for (int ks = 0; ks < 2; ++ks) {                            \
      bf16x8 af[2];                                                               \
      _Pragma("unroll") for (int mt = 0; mt < 2; ++mt) {                          \
        const int lr = (H)*64 + WM * 32 + mt * 16 + l15;                          \
        af[mt] = *(const bf16x8*)(Ab + lr * 128 +                                 \
                                  ((ks * 64 + l4 * 16) ^ ((lr & 7) << 4)));       \
      }                                                                           \
      __builtin_amdgcn_s_setprio(1);                                              \
      _Pragma("unroll") for (int mt = 0; mt < 2; ++mt)                            \
          _Pragma("unroll") for (int nt = 0; nt < 4; ++nt)                        \
              acc[H][mt][nt] = __builtin_amdgcn_mfma_f32_16x16x32_bf16(           \
                  af[mt], bfp[ks][nt], acc[H][mt][nt], 0, 0, 0);                  \
      __builtin_amdgcn_s_setprio(0);                                              \
    }                                                                             \
    asm volatile("" ::: "memory");                                                \
    __builtin_amdgcn_s_barrier();                                                 \
    asm volatile("" ::: "memory");                                                \
  }

  // prologue: buf0 <- kt0 (A + B = 8 outstanding)
  stage(1, 0, 0);
  stage(0, 0, 0);

  for (int i = 0; i < 8; ++i) {
    const int ktb1 = 2 * i + 1;
    const int ktb0 = (2 * i + 2 > 15) ? 15 : 2 * i + 2;  // clamp, never skip
    PRJ_PHASE(0, 0, 1, 1, ktb1, 4);  // read buf0 h0; stage A-buf1
    PRJ_PHASE(0, 1, 0, 1, ktb1, 8);  // read buf0 h1; stage B-buf1
    PRJ_PHASE(1, 0, 1, 0, ktb0, 4);  // read buf1 h0; stage A-buf0
    PRJ_PHASE(1, 1, 0, 0, ktb0, 8);  // read buf1 h1; stage B-buf0
  }
  asm volatile("s_waitcnt vmcnt(0)" ::: "memory");
  __builtin_amdgcn_s_barrier();
  asm volatile("" ::: "memory");

#pragma unroll
  for (int h = 0; h < 2; ++h)
#pragma unroll
    for (int mt = 0; mt < 2; ++mt)
#pragma unroll
      for (int nt = 0; nt < 4; ++nt)
#pragma unroll
        for (int r = 0; r < 4; ++r) {
          const int m = m0 + h * 64 + WM * 32 + mt * 16 + l4 * 4 + r;
          const int n = n0 + WN * 64 + nt * 16 + l15;
          out[(size_t)m * kC + n] = acc[h][mt][nt][r];
        }
#undef PRJ_PHASE
}

// ---------------- flash attention (causal), swapped-QK ----------------
// R11 structure with SINGLE barrier per tile: head = vmcnt(0)+s_barrier
// (covers K/V-of-cur RAW across waves AND WAR on cur^1: all waves' previous
// reads precede the barrier; stage issues after it). Ones-row MFMA l-sum,
// defer-max, exp2-domain. LPT qt=31-y; XCD ~ bh%8.
__global__ __launch_bounds__(256, 4) void attn(const uint16_t* __restrict__ qb,
                                               const uint16_t* __restrict__ kb,
                                               const uint16_t* __restrict__ vT,
                                               uint16_t* __restrict__ y) {
  // LDS: K[2] @ 0/8192 | V[2] @ 16384/24576 | P @ 32768 + wid*2048
  __shared__ __align__(1024) char lds[40960];
  const int lane = threadIdx.x & 63;
  const int wid = threadIdx.x >> 6;
  const int l15 = lane & 15, l4 = lane >> 4;
  const int bh = blockIdx.x;
  const int qt = (int)(gridDim.y - 1) - (int)blockIdx.y;  // LPT: long first
  const int q0 = qt * 64 + wid * 16;  // this wave's first q row
  const size_t base = (size_t)bh * kT * kD;
  const uint16_t* Q = qb + base;
  const uint16_t* Kp = kb + base;
  const uint16_t* Vt = vT + base;
  char* P = lds + 32768 + wid * 2048;
  const int xr = (l15 & 7) << 4;

  // Q fragments, scaled by log2(e)/sqrt(d) (exp2-domain softmax)
  bf16x8 qf[2];
#pragma unroll
  for (int ks = 0; ks < 2; ++ks) {
    bf16x8 t = *(const bf16x8*)(Q + (size_t)(q0 + l15) * kD + ks * 32 + l4 * 8);
#pragma unroll
    for (int i = 0; i < 8; ++i) t[i] = (__bf16)((float)t[i] * 0.1803368801f);
    qf[ks] = t;
  }
  bf16x8 ones;
#pragma unroll
  for (int i = 0; i < 8; ++i) ones[i] = (__bf16)1.0f;

  float m_ = -1e30f;                // per-lane; kept row-uniform
  f32x4 o[4];                       // O^T[d = nt*16 + l4*4 + r][q = l15]
  f32x4 ol = {0.f, 0.f, 0.f, 0.f};  // ones-row accumulator: ol[*] = l(q=l15)
#pragma unroll
  for (int nt = 0; nt < 4; ++nt) o[nt] = (f32x4){0.f, 0.f, 0.f, 0.f};

  const int nkt = qt + 1;  // wave-uniform

  auto STAGE = [&](int bi, int k0) {
#pragma unroll
    for (int c = 0; c < 2; ++c) {
      const int call = wid * 2 + c;
      const int row = call * 8 + (lane >> 3);
      const int colb = (((lane & 7) ^ ((lane >> 3) & 7)) << 4);
      gl_lds16((const char*)Kp + ((size_t)(k0 + row) * kD) * 2 + colb,
               lds + bi * 8192 + call * 1024);
      gl_lds16((const char*)Vt + ((size_t)row * kT + k0) * 2 + colb,
               lds + 16384 + bi * 8192 + call * 1024);
    }
  };

  int cur = 0;
  STAGE(0, 0);
  for (int kt = 0; kt < nkt; ++kt) {
    const int k0 = kt * 64;
    // single head barrier: own stages drained, then block-wide sync
    asm volatile("s_waitcnt vmcnt(0)" ::: "memory");
    __builtin_amdgcn_s_barrier();
    asm volatile("" ::: "memory");
    if (kt + 1 < nkt) STAGE(cur ^ 1, k0 + 64);  // WAR-safe: after barrier

    const char* Kb = lds + cur * 8192;
    const char* Vb = lds + 16384 + cur * 8192;

    // S^T = K Q^T (log2-domain)
    f32x4 s[4] = {};
    __builtin_amdgcn_s_setprio(1);
#pragma unroll
    for (int ks = 0; ks < 2; ++ks)
#pragma unroll
      for (int nt = 0; nt < 4; ++nt) {
        const bf16x8 kf =
            *(const bf16x8*)(Kb + (nt * 16 + l15) * 128 + ((ks * 64 + l4 * 16) ^ xr));
        s[nt] = __builtin_amdgcn_mfma_f32_16x16x32_bf16(kf, qf[ks], s[nt], 0, 0, 0);
      }
    __builtin_amdgcn_s_setprio(0);

    if (kt == nkt - 1) {  // causal mask on diagonal tile
      const int qq = q0 + l15;
#pragma unroll
      for (int nt = 0; nt < 4; ++nt)
#pragma unroll
        for (int r = 0; r < 4; ++r)
          if (k0 + nt * 16 + l4 * 4 + r > qq) s[nt][r] = -1e30f;
    }

    // online softmax, defer-max; row-sum via ones-row MFMA below
    float pm = s[0][0];
#pragma unroll
    for (int nt = 0; nt < 4; ++nt)
#pragma unroll
      for (int r = 0; r < 4; ++r) pm = fmaxf(pm, s[nt][r]);
    if (!__all(pm <= m_ + 11.0f)) {
      float rm = fmaxf(pm, __shfl_xor(pm, 16));
      rm = fmaxf(rm, __shfl_xor(rm, 32));
      const float newm = fmaxf(m_, rm);
      const float sc = exp2f(m_ - newm);
      m_ = newm;
#pragma unroll
      for (int nt = 0; nt < 4; ++nt)
#pragma unroll
        for (int r = 0; r < 4; ++r) o[nt][r] *= sc;
#pragma unroll
      for (int r = 0; r < 4; ++r) ol[r] *= sc;
    }
#pragma unroll
    for (int nt = 0; nt < 4; ++nt)
#pragma unroll
      for (int r = 0; r < 4; ++r) s[nt][r] = exp2f(s[nt][r] - m_);

    // P -> LDS (bf16, 8B packed, XOR-swizzled; per-wave slab)
#pragma unroll
    for (int nt = 0; nt < 4; ++nt) {
      bf16x4 pk;
#pragma unroll
      for (int r = 0; r < 4; ++r) pk[r] = (__bf16)s[nt][r];
      *(bf16x4*)(P + l15 * 128 + ((nt * 32 + l4 * 8) ^ xr)) = pk;
    }
    asm volatile("s_waitcnt lgkmcnt(0)" ::: "memory");
    __builtin_amdgcn_sched_barrier(0);

    // O^T += V^T P^T ; l += 1^T P^T (ones-row on the matrix pipe)
    bf16x8 pf[2];
#pragma unroll
    for (int ks = 0; ks < 2; ++ks)
      pf[ks] = *(const bf16x8*)(P + l15 * 128 + ((ks * 64 + l4 * 16) ^ xr));
    __builtin_amdgcn_s_setprio(1);
#pragma unroll
    for (int ks = 0; ks < 2; ++ks) {
#pragma unroll
      for (int nt = 0; nt < 4; ++nt) {
        const bf16x8 vf =
            *(const bf16x8*)(Vb + (nt * 16 + l15) * 128 + ((ks * 64 + l4 * 16) ^ xr));
        o[nt] = __builtin_amdgcn_mfma_f32_16x16x32_bf16(vf, pf[ks], o[nt], 0, 0, 0);
      }
      ol = __builtin_amdgcn_mfma_f32_16x16x32_bf16(ones, pf[ks], ol, 0, 0, 0);
    }
    __builtin_amdgcn_s_setprio(0);

    cur ^= 1;
  }

  // epilogue: ol[0] holds the full row-sum (MFMA reduced over K)
  const float inv = 1.0f / ol[0];
  const int b = bh >> 4, h = bh & 15;
  const int q = q0 + l15;
#pragma unroll
  for (int nt = 0; nt < 4; ++nt) {
    bf16x4 yv;
#pragma unroll
    for (int r = 0; r < 4; ++r) yv[r] = (__bf16)(o[nt][r] * inv);
    *(bf16x4*)(y + ((size_t)(b * kT + q)) * kC + h * kD + nt * 16 + l4 * 4) = yv;
  }
}

extern "C" void kernel_launch(void* const* d_in, const int* in_sizes, int n_in,
                              void* d_out, int out_size, void* d_ws, size_t ws_size,
                              hipStream_t stream) {
  const float* x = (const float*)d_in[0];
  const float* wqkv = (const float*)d_in[1];
  const float* wproj = (const float*)d_in[2];
  const float* pe = (const float*)d_in[3];

  char* ws = (char*)d_ws;
  uint16_t* xp = (uint16_t*)(ws);                          // 8MB, reused as y
  uint16_t* wq = (uint16_t*)(ws + (size_t)(8u << 20));     // 6MB
  uint16_t* wp = (uint16_t*)(ws + (size_t)(14u << 20));    // 2MB
  uint16_t* qbuf = (uint16_t*)(ws + (size_t)(16u << 20));  // 8MB
  uint16_t* kbuf = (uint16_t*)(ws + (size_t)(24u << 20));  // 8MB
  uint16_t* vTb = (uint16_t*)(ws + (size_t)(32u << 20));   // 8MB (total 40MB)

  prep_all<<<dim3(8192), 256, 0, stream>>>(x, pe, wqkv, wproj, xp, wq, wp);

  // qkv = xp @ wqkv^T : M=4096, N=3072 (256^2 tiles, 192 blocks, 4-phase)
  gemm_qkv<<<dim3(192), 512, 0, stream>>>(xp, wq, qbuf, kbuf, vTb);

  // attention -> y (stored into xp buffer, [B,T,C] bf16)
  attn<<<dim3(kB * kH, kT / 64), 256, 0, stream>>>(qbuf, kbuf, vTb, xp);

  // out = y @ wproj^T : M=4096, N=1024, f32 out (128^2, 4-phase, 256 blocks)
  gemm_proj<<<dim3(256), 256, 0, stream>>>(xp, wp, (float*)d_out);
}